// Round 10
// baseline (807.417 us; speedup 1.0000x reference)
//
#include <hip/hip_runtime.h>
#include <hip/hip_bf16.h>

#define NNODES 50000
#define NEDGES 1600000
#define FNODE 32
#define FEDGE 8
#define HIDD 256
#define NGRAPH 64
#define GDIM 16
#define NACT 64
#define FEATD (HIDD + GDIM) // 272
#define PCH 8               // pool chunks per graph

typedef short bf16x8 __attribute__((ext_vector_type(8)));
typedef float f32x4 __attribute__((ext_vector_type(4)));
typedef __bf16 bf16x2 __attribute__((ext_vector_type(2)));

// ---------------- bf16 helpers ----------------

__device__ inline float bfl(uint u) {  // low 16 bits -> float
  union { uint i; float f; } v; v.i = u << 16; return v.f;
}
__device__ inline float bfh(uint u) {  // high 16 bits -> float
  union { uint i; float f; } v; v.i = u & 0xffff0000u; return v.f;
}
__device__ inline float bf1(ushort u) {
  union { uint i; float f; } v; v.i = ((uint)u) << 16; return v.f;
}
__device__ inline ushort f2b(float a) {
  __hip_bfloat16 h = __float2bfloat16(a);  // RNE
  return *(ushort*)&h;
}
__device__ inline uint packbf(float a, float b) {
  return (uint)f2b(a) | ((uint)f2b(b) << 16);
}

// dot2: a.lo*b.lo + a.hi*b.hi + c  (packed bf16 pairs) -- used by k_edge32
__device__ inline float dot2bf(uint a, uint b, float c) {
#if defined(__has_builtin)
#if __has_builtin(__builtin_amdgcn_fdot2_f32_bf16)
  union { uint u; bf16x2 v; } ua, ub;
  ua.u = a; ub.u = b;
  return __builtin_amdgcn_fdot2_f32_bf16(ua.v, ub.v, c, false);
#else
  return fmaf(bfl(a), bfl(b), fmaf(bfh(a), bfh(b), c));
#endif
#else
  return fmaf(bfl(a), bfl(b), fmaf(bfh(a), bfh(b), c));
#endif
}

// ---------------- CSR build ----------------

__global__ void k_zero_i32(int* __restrict__ p, int n) {
  int i = blockIdx.x * blockDim.x + threadIdx.x;
  if (i < n) p[i] = 0;
}

__global__ void k_scan1(int* __restrict__ data, int n, int* __restrict__ sums) {
  __shared__ int buf[1024];
  int gid = blockIdx.x * 1024 + threadIdx.x;
  int v = (gid < n) ? data[gid] : 0;
  buf[threadIdx.x] = v;
  __syncthreads();
  for (int d = 1; d < 1024; d <<= 1) {
    int t = (threadIdx.x >= d) ? buf[threadIdx.x - d] : 0;
    __syncthreads();
    buf[threadIdx.x] += t;
    __syncthreads();
  }
  if (gid < n) data[gid] = buf[threadIdx.x];
  if (threadIdx.x == 1023) sums[blockIdx.x] = buf[1023];
}

// scan3 with inline cross-block prefix (sums are raw block totals) + cur copy
__global__ void k_scan3(int* __restrict__ data, int n, const int* __restrict__ sums,
                        int* __restrict__ cur) {
  int base = 0;
  for (int i = 0; i < (int)blockIdx.x; ++i) base += sums[i];  // <=48 iters
  int gid = blockIdx.x * 1024 + threadIdx.x;
  if (gid < n) {
    int v = data[gid] + base;
    data[gid] = v;
    if (gid < NNODES) cur[gid] = v;
  }
}

// scatter-lite: only a 4B edge-id goes to a random position (6.4MB target,
// L2-writeback-absorbed). The heavy payload moves in k_reorder with
// coalesced writes + random READS (cheap direction).
__global__ void k_scatter_lite(const int* __restrict__ dst, int* __restrict__ cur,
                               int* __restrict__ peid) {
  int e = blockIdx.x * blockDim.x + threadIdx.x;
  if (e >= NEDGES) return;
  int pos = atomicAdd(&cur[dst[e]], 1);
  peid[pos] = e;
}

// reorder: pos coalesced; e random-gathered; csr_src holds BYTE offsets
// (src*64: xb row = 64B; hb row = 512B = (src*64)<<3). eab bf16, CSR order.
__global__ void k_reorder(const int* __restrict__ peid, const int* __restrict__ src,
                          const float* __restrict__ ea, int* __restrict__ csr_src,
                          ushort* __restrict__ eab) {
  int pos = blockIdx.x * blockDim.x + threadIdx.x;
  if (pos >= NEDGES) return;
  int e = peid[pos];
  csr_src[pos] = src[e] * 64;
  float4 a = *(const float4*)&ea[(size_t)e * FEDGE];
  float4 b = *(const float4*)&ea[(size_t)e * FEDGE + 4];
  uint4 o;
  o.x = packbf(a.x, a.y);
  o.y = packbf(a.z, a.w);
  o.z = packbf(b.x, b.y);
  o.w = packbf(b.z, b.w);
  *(uint4*)&eab[(size_t)pos * FEDGE] = o;
}

// ------------ hist + fused prep (x->bf16, We pair-pack, W frag-pack) ---------

#define CVT_N (NNODES * FNODE / 4)           // 400000
#define WEP_N (128 + 3 * 1024)               // 3200
#define WP_N (1024 + 3 * 8192)               // 25600

__global__ void k_hist_prep(const int* __restrict__ dst, int* __restrict__ off,
                            const float* __restrict__ x, ushort* __restrict__ xb,
                            const float* __restrict__ We0, const float* __restrict__ We,
                            uint* __restrict__ wep0, uint* __restrict__ wep,
                            const float* __restrict__ W0, const float* __restrict__ W,
                            ushort* __restrict__ wp0, ushort* __restrict__ wp) {
  int gid = blockIdx.x * blockDim.x + threadIdx.x;
  if (gid < NEDGES) atomicAdd(&off[dst[gid] + 1], 1);
  int i = gid;
  if (i < CVT_N) {
    float4 v = *(const float4*)&x[(size_t)i * 4];
    uint2 o;
    o.x = packbf(v.x, v.y);
    o.y = packbf(v.z, v.w);
    *(uint2*)&xb[(size_t)i * 4] = o;
    return;
  }
  i -= CVT_N;
  if (i < WEP_N) {
    if (i < 128) {
      int k2 = i >> 5, c = i & 31;
      wep0[i] = packbf(We0[(2 * k2) * FNODE + c], We0[(2 * k2 + 1) * FNODE + c]);
    } else {
      int u = i - 128;
      int l = u >> 10;
      int r = u & 1023;
      int k2 = r >> 8, c = r & 255;
      const float* Wl = We + (size_t)l * FEDGE * HIDD;
      wep[u] = packbf(Wl[(2 * k2) * HIDD + c], Wl[(2 * k2 + 1) * HIDD + c]);
    }
    return;
  }
  i -= WEP_N;
  if (i < WP_N) {
    if (i < 1024) {  // layer 0, K=32 (ks=0)
      int lane = i & 63;
      int nf = i >> 6;
      int col = nf * 16 + (lane & 15);
      int k0 = (lane >> 4) * 8;
      ushort o[8];
#pragma unroll
      for (int q = 0; q < 8; ++q) o[q] = f2b(W0[(size_t)(k0 + q) * HIDD + col]);
      *(uint4*)&wp0[(size_t)i * 8] = *(uint4*)o;
    } else {
      int u = i - 1024;
      int l = u / 8192;
      int r = u - l * 8192;
      int lane = r & 63;
      int frag = r >> 6;  // ks*16+nf
      int nf = frag & 15, ks = frag >> 4;
      int col = nf * 16 + (lane & 15);
      int k0 = ks * 32 + (lane >> 4) * 8;
      const float* Wl = W + (size_t)l * HIDD * HIDD;
      ushort o[8];
#pragma unroll
      for (int q = 0; q < 8; ++q) o[q] = f2b(Wl[(size_t)(k0 + q) * HIDD + col]);
      *(uint4*)&wp[(size_t)u * 8] = *(uint4*)o;
    }
  }
}

// ---------------- Layer 0 edge pull (d=32), dot2, byte-offset csr -------------

__global__ __launch_bounds__(256) void k_edge32(
    const float* __restrict__ x, const ushort* __restrict__ xb,
    const uint4* __restrict__ eab4, const uint* __restrict__ wep0,
    const int* __restrict__ off, const int* __restrict__ csr_src,
    ushort* __restrict__ t0b) {
  int wid = __builtin_amdgcn_readfirstlane(
      (int)((blockIdx.x * blockDim.x + threadIdx.x) >> 6));
  if (wid >= NNODES) return;
  int lane = threadIdx.x & 63;
  int j = lane >> 5;
  int c = lane & 31;
  uint c2 = (uint)c * 2;
  const char* xbase = (const char*)xb;
  uint w0 = wep0[c], w1 = wep0[32 + c], w2 = wep0[64 + c], w3 = wep0[96 + c];
  int s0 = off[wid], s1 = off[wid + 1];
  float acc = 0.f;
  int e = s0 + j;
  for (; e + 6 < s1; e += 8) {  // 4 edges per half-wave in flight
    ushort hA = *(const ushort*)(xbase + ((uint)csr_src[e] + c2));
    ushort hB = *(const ushort*)(xbase + ((uint)csr_src[e + 2] + c2));
    ushort hC = *(const ushort*)(xbase + ((uint)csr_src[e + 4] + c2));
    ushort hD = *(const ushort*)(xbase + ((uint)csr_src[e + 6] + c2));
    uint4 eA = eab4[e];
    uint4 eB = eab4[e + 2];
    uint4 eC = eab4[e + 4];
    uint4 eD = eab4[e + 6];
    float pr;
#define B32(hu, eu)                 \
    pr = bf1(hu);                   \
    pr = dot2bf(eu.x, w0, pr);      \
    pr = dot2bf(eu.y, w1, pr);      \
    pr = dot2bf(eu.z, w2, pr);      \
    pr = dot2bf(eu.w, w3, pr);      \
    acc += fmaxf(pr, 0.f);
    B32(hA, eA) B32(hB, eB) B32(hC, eC) B32(hD, eD)
  }
  for (; e < s1; e += 2) {
    ushort hu = *(const ushort*)(xbase + ((uint)csr_src[e] + c2));
    uint4 eu = eab4[e];
    float pr;
    B32(hu, eu)
#undef B32
  }
  acc += __shfl_xor(acc, 32);
  if (j == 0) t0b[wid * FNODE + c] = f2b(x[wid * FNODE + c] + acc);
}

// ------- Layers 1-3 edge pull (d=256): scalar-pipe edge attrs, fp32 weights ---
// Edge attrs are wave-uniform -> their bf16->f32 unpacks stay on the SCALAR
// pipe; per-lane work is 32 v_fmac_f32 (SGPR x VGPR) + 4 h-unpacks + relu/acc.

__device__ inline void body_f(uint2 hu, uint4 eu, const float wf[8][4], float4& acc) {
  float ef0 = bfl(eu.x), ef1 = bfh(eu.x), ef2 = bfl(eu.y), ef3 = bfh(eu.y);
  float ef4 = bfl(eu.z), ef5 = bfh(eu.z), ef6 = bfl(eu.w), ef7 = bfh(eu.w);
  float p0 = bfl(hu.x), p1 = bfh(hu.x), p2 = bfl(hu.y), p3 = bfh(hu.y);
#define FK(ef, k)                       \
  p0 = fmaf(ef, wf[k][0], p0);          \
  p1 = fmaf(ef, wf[k][1], p1);          \
  p2 = fmaf(ef, wf[k][2], p2);          \
  p3 = fmaf(ef, wf[k][3], p3);
  FK(ef0, 0) FK(ef1, 1) FK(ef2, 2) FK(ef3, 3)
  FK(ef4, 4) FK(ef5, 5) FK(ef6, 6) FK(ef7, 7)
#undef FK
  acc.x += fmaxf(p0, 0.f);
  acc.y += fmaxf(p1, 0.f);
  acc.z += fmaxf(p2, 0.f);
  acc.w += fmaxf(p3, 0.f);
}

// load chunk of 4 edges starting at eb into (H, E_)
#define LOADCH(H, E_, eb)                                                   \
  _Pragma("unroll") for (int u = 0; u < 4; ++u) {                           \
    uint boff = ((uint)csr_src[(eb) + u] << 3) + c8;                        \
    H[u] = *(const uint2*)(hbase + boff);                                   \
  }                                                                         \
  _Pragma("unroll") for (int u = 0; u < 4; ++u) E_[u] = eab4[(eb) + u];

#define COMPCH(H, E_)                                                       \
  _Pragma("unroll") for (int u = 0; u < 4; ++u)                             \
    body_f(H[u], E_[u], wf, (u & 1) ? acc1 : acc0);

__global__ __launch_bounds__(256) void k_edge256(
    const ushort* __restrict__ hb, const uint4* __restrict__ eab4,
    const uint* __restrict__ wepl, const int* __restrict__ off,
    const int* __restrict__ csr_src, ushort* __restrict__ tb) {
  int wid = __builtin_amdgcn_readfirstlane(
      (int)((blockIdx.x * blockDim.x + threadIdx.x) >> 6));
  if (wid >= NNODES) return;
  int lane = threadIdx.x & 63;
  int c = lane * 4;
  uint c8 = (uint)lane * 8;
  const char* hbase = (const char*)hb;
  float wf[8][4];  // fp32 weights: 32 VGPR, zero unpacks in the loop
#pragma unroll
  for (int k2 = 0; k2 < 4; ++k2) {
    uint4 pq = *(const uint4*)&wepl[k2 * HIDD + c];
    wf[2 * k2][0] = bfl(pq.x); wf[2 * k2 + 1][0] = bfh(pq.x);
    wf[2 * k2][1] = bfl(pq.y); wf[2 * k2 + 1][1] = bfh(pq.y);
    wf[2 * k2][2] = bfl(pq.z); wf[2 * k2 + 1][2] = bfh(pq.z);
    wf[2 * k2][3] = bfl(pq.w); wf[2 * k2 + 1][3] = bfh(pq.w);
  }
  int s0 = off[wid], s1 = off[wid + 1];
  float4 acc0 = {0.f, 0.f, 0.f, 0.f}, acc1 = {0.f, 0.f, 0.f, 0.f};
  int e = s0;
  int nch = (s1 - s0) >> 2;  // chunks of 4
  if (nch > 0) {
    uint2 hA[4], hB[4];
    uint4 EA[4], EB[4];
    LOADCH(hA, EA, e)
    int t = 1;
    for (; t + 1 < nch; t += 2) {  // 2 chunks per iteration, no reg rotation
      LOADCH(hB, EB, e + 4)
      COMPCH(hA, EA)
      LOADCH(hA, EA, e + 8)
      COMPCH(hB, EB)
      e += 8;
    }
    if (t < nch) {  // one trailing chunk beyond the loaded hA
      LOADCH(hB, EB, e + 4)
      COMPCH(hA, EA)
      COMPCH(hB, EB)
      e += 8;
    } else {
      COMPCH(hA, EA)
      e += 4;
    }
  }
  for (; e < s1; ++e) {  // tail <= 3 edges
    uint boff = ((uint)csr_src[e] << 3) + c8;
    uint2 hu = *(const uint2*)(hbase + boff);
    uint4 eu = eab4[e];
    body_f(hu, eu, wf, acc0);
  }

  uint2 su = *(const uint2*)&hb[(size_t)wid * HIDD + c];  // self term (bf16)
  float4 o;
  o.x = bfl(su.x) + acc0.x + acc1.x;
  o.y = bfh(su.x) + acc0.y + acc1.y;
  o.z = bfl(su.y) + acc0.z + acc1.z;
  o.w = bfh(su.y) + acc0.w + acc1.w;
  uint2 ob;
  ob.x = packbf(o.x, o.y);
  ob.y = packbf(o.z, o.w);
  *(uint2*)&tb[(size_t)wid * HIDD + c] = ob;
}
#undef LOADCH
#undef COMPCH

// -------- MFMA node-update GEMM v4: B staged in LDS (32KB stages), A direct ---

template <int K>
__global__ __launch_bounds__(256) void k_gemm_mfma(
    const ushort* __restrict__ Tb, const ushort* __restrict__ Wp,
    const float* __restrict__ bias, ushort* __restrict__ outb, int nrows) {
  constexpr int KS = K / 32;               // ks-groups total (8 or 1)
  constexpr int KSH = (KS >= 2) ? 2 : KS;  // ks-groups per LDS stage
  constexpr int CH = KSH * 16 * 64;        // 16B chunks per stage
  __shared__ ushort bl[CH * 8];            // 32KB (K=256), 16KB (K=32)
  const int tid = threadIdx.x;
  const int wave = tid >> 6;
  const int lane = tid & 63;
  const int row0 = blockIdx.x * 64 + wave * 16;
  const int arow = row0 + (lane & 15);
  const int kgrp = lane >> 4;  // 0..3
  f32x4 acc[16];
#pragma unroll
  for (int nf = 0; nf < 16; ++nf) acc[nf] = (f32x4){0.f, 0.f, 0.f, 0.f};
#pragma unroll
  for (int st = 0; st < KS / KSH; ++st) {
    __syncthreads();  // protect previous stage's reads
#pragma unroll
    for (int chk = 0; chk < CH / 256; ++chk) {
      int ch = chk * 256 + tid;
      *(uint4*)&bl[(size_t)ch * 8] = *(const uint4*)&Wp[((size_t)st * CH + ch) * 8];
    }
    __syncthreads();
#pragma unroll
    for (int ksl = 0; ksl < KSH; ++ksl) {
      int ks = st * KSH + ksl;
      bf16x8 af = *(const bf16x8*)&Tb[(size_t)arow * K + ks * 32 + kgrp * 8];
#pragma unroll
      for (int nf = 0; nf < 16; ++nf) {
        bf16x8 bfg = *(const bf16x8*)&bl[((size_t)(ksl * 16 + nf) * 64 + lane) * 8];
        acc[nf] = __builtin_amdgcn_mfma_f32_16x16x32_bf16(af, bfg, acc[nf], 0, 0, 0);
      }
    }
  }
  const int ocol0 = lane & 15;
  const int orow0 = row0 + (lane >> 4) * 4;
#pragma unroll
  for (int nf = 0; nf < 16; ++nf) {
    int col = nf * 16 + ocol0;
    float bv = bias[col];
#pragma unroll
    for (int r = 0; r < 4; ++r) {
      int row = orow0 + r;
      if (row < nrows) outb[(size_t)row * HIDD + col] = f2b(fmaxf(acc[nf][r] + bv, 0.f));
    }
  }
}

// ---------------- Mean pool per graph (batch sorted, h in bf16) ---------------

__global__ void k_pool_partial(const ushort* __restrict__ hb, const int* __restrict__ batch,
                               float* __restrict__ fp) {  // fp[PCH][NGRAPH][HIDD]
  int b = blockIdx.x >> 3;
  int j = blockIdx.x & 7;
  __shared__ int srange[2];
  if (threadIdx.x < 2) {
    int target = b + threadIdx.x;
    int lo = 0, hi = NNODES;
    while (lo < hi) {
      int mid = (lo + hi) >> 1;
      if (batch[mid] < target) lo = mid + 1; else hi = mid;
    }
    srange[threadIdx.x] = lo;
  }
  __syncthreads();
  int s = srange[0], eend = srange[1];
  int len = eend - s;
  int cs = s + (int)((long long)len * j / PCH);
  int ce = s + (int)((long long)len * (j + 1) / PCH);
  int col = threadIdx.x;
  float acc = 0.f;
  for (int n = cs; n < ce; ++n) acc += bf1(hb[(size_t)n * HIDD + col]);
  fp[((size_t)j * NGRAPH + b) * HIDD + col] = acc;
}

// ---------------- pool-final + heads fused (block per graph) ------------------

__global__ void k_pool_heads(const float* __restrict__ fp, const int* __restrict__ batch,
                             const float* __restrict__ gf, const float* __restrict__ Wp,
                             const float* __restrict__ bp, const float* __restrict__ Wv,
                             const float* __restrict__ bv, float* __restrict__ out) {
  int b = blockIdx.x;
  __shared__ float f[FEATD];
  __shared__ int srange[2];
  if (threadIdx.x < 2) {
    int target = b + threadIdx.x;
    int lo = 0, hi = NNODES;
    while (lo < hi) {
      int mid = (lo + hi) >> 1;
      if (batch[mid] < target) lo = mid + 1; else hi = mid;
    }
    srange[threadIdx.x] = lo;
  }
  __syncthreads();
  int col = threadIdx.x;
  float acc = 0.f;
#pragma unroll
  for (int j = 0; j < PCH; ++j) acc += fp[((size_t)j * NGRAPH + b) * HIDD + col];
  float cnt = fmaxf((float)(srange[1] - srange[0]), 1.0f);
  f[col] = acc / cnt;
  if (col < GDIM) f[HIDD + col] = gf[b * GDIM + col];
  __syncthreads();
  if (col < NACT) {  // wave 0: logits
    float lg = bp[col];
    for (int k = 0; k < FEATD; ++k) lg = fmaf(f[k], Wp[k * NACT + col], lg);
    out[b * NACT + col] = lg;
  } else if (col < 128) {  // wave 1: value
    int t = col - 64;
    float pv = 0.f;
    for (int k = t; k < FEATD; k += 64) pv = fmaf(f[k], Wv[k], pv);
#pragma unroll
    for (int d = 32; d > 0; d >>= 1) pv += __shfl_down(pv, d);
    if (t == 0) out[NGRAPH * NACT + b] = pv + bv[0];
  }
}

// ---------------- launch ----------------

extern "C" void kernel_launch(void* const* d_in, const int* in_sizes, int n_in,
                              void* d_out, int out_size, void* d_ws, size_t ws_size,
                              hipStream_t stream) {
  const float* x   = (const float*)d_in[0];
  const float* ea  = (const float*)d_in[1];
  const float* gf  = (const float*)d_in[2];
  const float* We0 = (const float*)d_in[3];
  const float* W0  = (const float*)d_in[4];
  const float* b0  = (const float*)d_in[5];
  const float* We  = (const float*)d_in[6];
  const float* W   = (const float*)d_in[7];
  const float* bb  = (const float*)d_in[8];
  const float* Wp  = (const float*)d_in[9];
  const float* bp  = (const float*)d_in[10];
  const float* Wv  = (const float*)d_in[11];
  const float* bv  = (const float*)d_in[12];
  const int* eidx  = (const int*)d_in[13];
  const int* batch = (const int*)d_in[14];
  const int* esrc = eidx;
  const int* edst = eidx + NEDGES;

  char* w = (char*)d_ws;
  size_t p = 0;
  auto take = [&](size_t bytes) {
    size_t r = p;
    p += (bytes + 255) & ~(size_t)255;
    return r;
  };
  int* off      = (int*)(w + take((NNODES + 1) * 4));
  int* cur      = (int*)(w + take(NNODES * 4));
  int* sums     = (int*)(w + take(1024));
  int* peid     = (int*)(w + take((size_t)NEDGES * 4));
  int* csr_src  = (int*)(w + take((size_t)NEDGES * 4));
  ushort* eab   = (ushort*)(w + take((size_t)NEDGES * FEDGE * 2));
  ushort* t0b   = (ushort*)(w + take((size_t)NNODES * FNODE * 2));
  ushort* xb    = (ushort*)(w + take((size_t)NNODES * FNODE * 2));
  ushort* tb    = (ushort*)(w + take((size_t)NNODES * HIDD * 2));
  ushort* hb    = (ushort*)(w + take((size_t)NNODES * HIDD * 2));
  uint* wep0    = (uint*)(w + take(128 * 4));
  uint* wepb    = (uint*)(w + take(3 * 1024 * 4));
  ushort* wp0   = (ushort*)(w + take((size_t)1024 * 8 * 2));
  ushort* wpb   = (ushort*)(w + take((size_t)3 * 8192 * 8 * 2));
  float* fp     = (float*)(w + take((size_t)PCH * NGRAPH * HIDD * 4));
  if (p > ws_size) return;  // workspace too small -> visible failure

  // CSR by dst: hist(+prep) -> scan -> scatter-lite(eid) -> gather-reorder
  k_zero_i32<<<(NNODES + 1 + 255) / 256, 256, 0, stream>>>(off, NNODES + 1);
  k_hist_prep<<<(NEDGES + 255) / 256, 256, 0, stream>>>(
      edst, off, x, xb, We0, We, wep0, wepb, W0, W, wp0, wpb);
  int n_scan = NNODES + 1;
  int nb_scan = (n_scan + 1023) / 1024;
  k_scan1<<<nb_scan, 1024, 0, stream>>>(off, n_scan, sums);
  k_scan3<<<nb_scan, 1024, 0, stream>>>(off, n_scan, sums, cur);
  k_scatter_lite<<<(NEDGES + 255) / 256, 256, 0, stream>>>(edst, cur, peid);
  k_reorder<<<(NEDGES + 255) / 256, 256, 0, stream>>>(peid, esrc, ea, csr_src, eab);

  const int gemm_grid = (NNODES + 63) / 64;  // 64 rows/block, 4 waves

  // layer 0
  k_edge32<<<NNODES / 4, 256, 0, stream>>>(x, xb, (const uint4*)eab, wep0, off,
                                           csr_src, t0b);
  k_gemm_mfma<FNODE><<<gemm_grid, 256, 0, stream>>>(t0b, wp0, b0, hb, NNODES);

  // layers 1..3: edge pull (bf16 gather) -> bf16 t -> MFMA GEMM -> bf16 h
  for (int l = 0; l < 3; ++l) {
    k_edge256<<<NNODES / 4, 256, 0, stream>>>(hb, (const uint4*)eab, wepb + l * 1024,
                                              off, csr_src, tb);
    k_gemm_mfma<HIDD><<<gemm_grid, 256, 0, stream>>>(
        tb, wpb + (size_t)l * 8192 * 8, bb + (size_t)l * HIDD, hb, NNODES);
  }

  // pool + heads
  k_pool_partial<<<NGRAPH * PCH, HIDD, 0, stream>>>(hb, batch, fp);
  k_pool_heads<<<NGRAPH, HIDD, 0, stream>>>(fp, batch, gf, Wp, bp, Wv, bv,
                                            (float*)d_out);
}

// Round 11
// 642.117 us; speedup vs baseline: 1.2574x; 1.2574x over previous
//
#include <hip/hip_runtime.h>
#include <hip/hip_bf16.h>

#define NNODES 50000
#define NEDGES 1600000
#define FNODE 32
#define FEDGE 8
#define HIDD 256
#define NGRAPH 64
#define GDIM 16
#define NACT 64
#define FEATD (HIDD + GDIM) // 272
#define PCH 8               // pool chunks per graph

typedef short bf16x8 __attribute__((ext_vector_type(8)));
typedef float f32x4 __attribute__((ext_vector_type(4)));
typedef __bf16 bf16x2 __attribute__((ext_vector_type(2)));

// ---------------- bf16 helpers ----------------

__device__ inline float bfl(uint u) {  // low 16 bits -> float
  union { uint i; float f; } v; v.i = u << 16; return v.f;
}
__device__ inline float bfh(uint u) {  // high 16 bits -> float
  union { uint i; float f; } v; v.i = u & 0xffff0000u; return v.f;
}
__device__ inline float bf1(ushort u) {
  union { uint i; float f; } v; v.i = ((uint)u) << 16; return v.f;
}
__device__ inline ushort f2b(float a) {
  __hip_bfloat16 h = __float2bfloat16(a);  // RNE
  return *(ushort*)&h;
}
__device__ inline uint packbf(float a, float b) {
  return (uint)f2b(a) | ((uint)f2b(b) << 16);
}

// dot2: a.lo*b.lo + a.hi*b.hi + c  (packed bf16 pairs)
__device__ inline float dot2bf(uint a, uint b, float c) {
#if defined(__has_builtin)
#if __has_builtin(__builtin_amdgcn_fdot2_f32_bf16)
  union { uint u; bf16x2 v; } ua, ub;
  ua.u = a; ub.u = b;
  return __builtin_amdgcn_fdot2_f32_bf16(ua.v, ub.v, c, false);
#else
  return fmaf(bfl(a), bfl(b), fmaf(bfh(a), bfh(b), c));
#endif
#else
  return fmaf(bfl(a), bfl(b), fmaf(bfh(a), bfh(b), c));
#endif
}

// ---------------- CSR build ----------------

__global__ void k_zero_i32(int* __restrict__ p, int n) {
  int i = blockIdx.x * blockDim.x + threadIdx.x;
  if (i < n) p[i] = 0;
}

__global__ void k_scan1(int* __restrict__ data, int n, int* __restrict__ sums) {
  __shared__ int buf[1024];
  int gid = blockIdx.x * 1024 + threadIdx.x;
  int v = (gid < n) ? data[gid] : 0;
  buf[threadIdx.x] = v;
  __syncthreads();
  for (int d = 1; d < 1024; d <<= 1) {
    int t = (threadIdx.x >= d) ? buf[threadIdx.x - d] : 0;
    __syncthreads();
    buf[threadIdx.x] += t;
    __syncthreads();
  }
  if (gid < n) data[gid] = buf[threadIdx.x];
  if (threadIdx.x == 1023) sums[blockIdx.x] = buf[1023];
}

// scan3 with inline cross-block prefix (sums are raw block totals)
__global__ void k_scan3(int* __restrict__ data, int n, const int* __restrict__ sums) {
  int base = 0;
  for (int i = 0; i < (int)blockIdx.x; ++i) base += sums[i];  // <=48 iters
  int gid = blockIdx.x * 1024 + threadIdx.x;
  if (blockIdx.x > 0 && gid < n) data[gid] += base;
}

// atomic-free placement: pos = off[dst] + rank (rank captured during hist).
// Pure fire-and-forget random stores -- no atomic return-value dependency.
// csr_src holds BYTE offsets (src*64: xb row = 64B; hb row = (src*64)<<3).
__global__ void k_place(const int* __restrict__ src, const int* __restrict__ dst,
                        const int* __restrict__ rank, const int* __restrict__ off,
                        const float* __restrict__ ea, int* __restrict__ csr_src,
                        ushort* __restrict__ eab) {
  int e = blockIdx.x * blockDim.x + threadIdx.x;
  if (e >= NEDGES) return;
  int pos = off[dst[e]] + rank[e];
  csr_src[pos] = src[e] * 64;
  float4 a = *(const float4*)&ea[(size_t)e * FEDGE];
  float4 b = *(const float4*)&ea[(size_t)e * FEDGE + 4];
  uint4 o;
  o.x = packbf(a.x, a.y);
  o.y = packbf(a.z, a.w);
  o.z = packbf(b.x, b.y);
  o.w = packbf(b.z, b.w);
  *(uint4*)&eab[(size_t)pos * FEDGE] = o;
}

// ------------ hist (rank-capturing) + fused prep --------------------------

#define CVT_N (NNODES * FNODE / 4)           // 400000
#define WEP_N (128 + 3 * 1024)               // 3200
#define WP_N (1024 + 3 * 8192)               // 25600

__global__ void k_hist_prep(const int* __restrict__ dst, int* __restrict__ off,
                            int* __restrict__ rank,
                            const float* __restrict__ x, ushort* __restrict__ xb,
                            const float* __restrict__ We0, const float* __restrict__ We,
                            uint* __restrict__ wep0, uint* __restrict__ wep,
                            const float* __restrict__ W0, const float* __restrict__ W,
                            ushort* __restrict__ wp0, ushort* __restrict__ wp) {
  int gid = blockIdx.x * blockDim.x + threadIdx.x;
  if (gid < NEDGES) rank[gid] = atomicAdd(&off[dst[gid] + 1], 1);  // rank = old count
  int i = gid;
  if (i < CVT_N) {
    float4 v = *(const float4*)&x[(size_t)i * 4];
    uint2 o;
    o.x = packbf(v.x, v.y);
    o.y = packbf(v.z, v.w);
    *(uint2*)&xb[(size_t)i * 4] = o;
    return;
  }
  i -= CVT_N;
  if (i < WEP_N) {
    if (i < 128) {
      int k2 = i >> 5, c = i & 31;
      wep0[i] = packbf(We0[(2 * k2) * FNODE + c], We0[(2 * k2 + 1) * FNODE + c]);
    } else {
      int u = i - 128;
      int l = u >> 10;
      int r = u & 1023;
      int k2 = r >> 8, c = r & 255;
      const float* Wl = We + (size_t)l * FEDGE * HIDD;
      wep[u] = packbf(Wl[(2 * k2) * HIDD + c], Wl[(2 * k2 + 1) * HIDD + c]);
    }
    return;
  }
  i -= WEP_N;
  if (i < WP_N) {
    if (i < 1024) {  // layer 0, K=32 (ks=0)
      int lane = i & 63;
      int nf = i >> 6;
      int col = nf * 16 + (lane & 15);
      int k0 = (lane >> 4) * 8;
      ushort o[8];
#pragma unroll
      for (int q = 0; q < 8; ++q) o[q] = f2b(W0[(size_t)(k0 + q) * HIDD + col]);
      *(uint4*)&wp0[(size_t)i * 8] = *(uint4*)o;
    } else {
      int u = i - 1024;
      int l = u / 8192;
      int r = u - l * 8192;
      int lane = r & 63;
      int frag = r >> 6;  // ks*16+nf
      int nf = frag & 15, ks = frag >> 4;
      int col = nf * 16 + (lane & 15);
      int k0 = ks * 32 + (lane >> 4) * 8;
      const float* Wl = W + (size_t)l * HIDD * HIDD;
      ushort o[8];
#pragma unroll
      for (int q = 0; q < 8; ++q) o[q] = f2b(Wl[(size_t)(k0 + q) * HIDD + col]);
      *(uint4*)&wp[(size_t)u * 8] = *(uint4*)o;
    }
  }
}

// ---------------- Layer 0 edge pull (d=32), dot2, byte-offset csr -------------

__global__ __launch_bounds__(256) void k_edge32(
    const float* __restrict__ x, const ushort* __restrict__ xb,
    const uint4* __restrict__ eab4, const uint* __restrict__ wep0,
    const int* __restrict__ off, const int* __restrict__ csr_src,
    ushort* __restrict__ t0b) {
  int wid = __builtin_amdgcn_readfirstlane(
      (int)((blockIdx.x * blockDim.x + threadIdx.x) >> 6));
  if (wid >= NNODES) return;
  int lane = threadIdx.x & 63;
  int j = lane >> 5;
  int c = lane & 31;
  uint c2 = (uint)c * 2;
  const char* xbase = (const char*)xb;
  uint w0 = wep0[c], w1 = wep0[32 + c], w2 = wep0[64 + c], w3 = wep0[96 + c];
  int s0 = off[wid], s1 = off[wid + 1];
  float acc = 0.f;
  int e = s0 + j;
  for (; e + 6 < s1; e += 8) {  // 4 edges per half-wave in flight
    ushort hA = *(const ushort*)(xbase + ((uint)csr_src[e] + c2));
    ushort hB = *(const ushort*)(xbase + ((uint)csr_src[e + 2] + c2));
    ushort hC = *(const ushort*)(xbase + ((uint)csr_src[e + 4] + c2));
    ushort hD = *(const ushort*)(xbase + ((uint)csr_src[e + 6] + c2));
    uint4 eA = eab4[e];
    uint4 eB = eab4[e + 2];
    uint4 eC = eab4[e + 4];
    uint4 eD = eab4[e + 6];
    float pr;
#define B32(hu, eu)                 \
    pr = bf1(hu);                   \
    pr = dot2bf(eu.x, w0, pr);      \
    pr = dot2bf(eu.y, w1, pr);      \
    pr = dot2bf(eu.z, w2, pr);      \
    pr = dot2bf(eu.w, w3, pr);      \
    acc += fmaxf(pr, 0.f);
    B32(hA, eA) B32(hB, eB) B32(hC, eC) B32(hD, eD)
  }
  for (; e < s1; e += 2) {
    ushort hu = *(const ushort*)(xbase + ((uint)csr_src[e] + c2));
    uint4 eu = eab4[e];
    float pr;
    B32(hu, eu)
#undef B32
  }
  acc += __shfl_xor(acc, 32);
  if (j == 0) t0b[wid * FNODE + c] = f2b(x[wid * FNODE + c] + acc);
}

// ------- Layers 1-3 edge pull (d=256), unrolled x2 software pipeline ----------

__device__ inline void body_dot(uint2 hu, uint4 eu, const uint4 wq[4], float4& acc) {
  float4 pr;
  pr.x = bfl(hu.x);
  pr.y = bfh(hu.x);
  pr.z = bfl(hu.y);
  pr.w = bfh(hu.y);
  pr.x = dot2bf(eu.x, wq[0].x, pr.x);
  pr.x = dot2bf(eu.y, wq[1].x, pr.x);
  pr.x = dot2bf(eu.z, wq[2].x, pr.x);
  pr.x = dot2bf(eu.w, wq[3].x, pr.x);
  pr.y = dot2bf(eu.x, wq[0].y, pr.y);
  pr.y = dot2bf(eu.y, wq[1].y, pr.y);
  pr.y = dot2bf(eu.z, wq[2].y, pr.y);
  pr.y = dot2bf(eu.w, wq[3].y, pr.y);
  pr.z = dot2bf(eu.x, wq[0].z, pr.z);
  pr.z = dot2bf(eu.y, wq[1].z, pr.z);
  pr.z = dot2bf(eu.z, wq[2].z, pr.z);
  pr.z = dot2bf(eu.w, wq[3].z, pr.z);
  pr.w = dot2bf(eu.x, wq[0].w, pr.w);
  pr.w = dot2bf(eu.y, wq[1].w, pr.w);
  pr.w = dot2bf(eu.z, wq[2].w, pr.w);
  pr.w = dot2bf(eu.w, wq[3].w, pr.w);
  acc.x += fmaxf(pr.x, 0.f);
  acc.y += fmaxf(pr.y, 0.f);
  acc.z += fmaxf(pr.z, 0.f);
  acc.w += fmaxf(pr.w, 0.f);
}

// load chunk of 4 edges starting at eb into (H, E_)
#define LOADCH(H, E_, eb)                                                   \
  _Pragma("unroll") for (int u = 0; u < 4; ++u) {                           \
    uint boff = ((uint)csr_src[(eb) + u] << 3) + c8;                        \
    H[u] = *(const uint2*)(hbase + boff);                                   \
  }                                                                         \
  _Pragma("unroll") for (int u = 0; u < 4; ++u) E_[u] = eab4[(eb) + u];

#define COMPCH(H, E_)                                                       \
  _Pragma("unroll") for (int u = 0; u < 4; ++u)                             \
    body_dot(H[u], E_[u], wq, (u & 1) ? acc1 : acc0);

__global__ __launch_bounds__(256) void k_edge256(
    const ushort* __restrict__ hb, const uint4* __restrict__ eab4,
    const uint* __restrict__ wepl, const int* __restrict__ off,
    const int* __restrict__ csr_src, ushort* __restrict__ tb) {
  int wid = __builtin_amdgcn_readfirstlane(
      (int)((blockIdx.x * blockDim.x + threadIdx.x) >> 6));
  if (wid >= NNODES) return;
  int lane = threadIdx.x & 63;
  int c = lane * 4;
  uint c8 = (uint)lane * 8;
  const char* hbase = (const char*)hb;
  uint4 wq[4];
#pragma unroll
  for (int k2 = 0; k2 < 4; ++k2) wq[k2] = *(const uint4*)&wepl[k2 * HIDD + c];
  int s0 = off[wid], s1 = off[wid + 1];
  float4 acc0 = {0.f, 0.f, 0.f, 0.f}, acc1 = {0.f, 0.f, 0.f, 0.f};
  int e = s0;
  int nch = (s1 - s0) >> 2;  // chunks of 4
  if (nch > 0) {
    uint2 hA[4], hB[4];
    uint4 EA[4], EB[4];
    LOADCH(hA, EA, e)
    int t = 1;
    for (; t + 1 < nch; t += 2) {  // 2 chunks per iteration, no reg rotation
      LOADCH(hB, EB, e + 4)
      COMPCH(hA, EA)
      LOADCH(hA, EA, e + 8)
      COMPCH(hB, EB)
      e += 8;
    }
    if (t < nch) {  // one trailing chunk beyond the loaded hA
      LOADCH(hB, EB, e + 4)
      COMPCH(hA, EA)
      COMPCH(hB, EB)
      e += 8;
    } else {
      COMPCH(hA, EA)
      e += 4;
    }
  }
  for (; e < s1; ++e) {  // tail <= 3 edges
    uint boff = ((uint)csr_src[e] << 3) + c8;
    uint2 hu = *(const uint2*)(hbase + boff);
    uint4 eu = eab4[e];
    body_dot(hu, eu, wq, acc0);
  }

  uint2 su = *(const uint2*)&hb[(size_t)wid * HIDD + c];  // self term (bf16)
  float4 o;
  o.x = bfl(su.x) + acc0.x + acc1.x;
  o.y = bfh(su.x) + acc0.y + acc1.y;
  o.z = bfl(su.y) + acc0.z + acc1.z;
  o.w = bfh(su.y) + acc0.w + acc1.w;
  uint2 ob;
  ob.x = packbf(o.x, o.y);
  ob.y = packbf(o.z, o.w);
  *(uint2*)&tb[(size_t)wid * HIDD + c] = ob;
}
#undef LOADCH
#undef COMPCH

// -------- MFMA node-update GEMM v4: B staged in LDS (32KB stages), A direct ---

template <int K>
__global__ __launch_bounds__(256) void k_gemm_mfma(
    const ushort* __restrict__ Tb, const ushort* __restrict__ Wp,
    const float* __restrict__ bias, ushort* __restrict__ outb, int nrows) {
  constexpr int KS = K / 32;               // ks-groups total (8 or 1)
  constexpr int KSH = (KS >= 2) ? 2 : KS;  // ks-groups per LDS stage
  constexpr int CH = KSH * 16 * 64;        // 16B chunks per stage
  __shared__ ushort bl[CH * 8];            // 32KB (K=256), 16KB (K=32)
  const int tid = threadIdx.x;
  const int wave = tid >> 6;
  const int lane = tid & 63;
  const int row0 = blockIdx.x * 64 + wave * 16;
  const int arow = row0 + (lane & 15);
  const int kgrp = lane >> 4;  // 0..3
  f32x4 acc[16];
#pragma unroll
  for (int nf = 0; nf < 16; ++nf) acc[nf] = (f32x4){0.f, 0.f, 0.f, 0.f};
#pragma unroll
  for (int st = 0; st < KS / KSH; ++st) {
    __syncthreads();  // protect previous stage's reads
#pragma unroll
    for (int chk = 0; chk < CH / 256; ++chk) {
      int ch = chk * 256 + tid;
      *(uint4*)&bl[(size_t)ch * 8] = *(const uint4*)&Wp[((size_t)st * CH + ch) * 8];
    }
    __syncthreads();
#pragma unroll
    for (int ksl = 0; ksl < KSH; ++ksl) {
      int ks = st * KSH + ksl;
      bf16x8 af = *(const bf16x8*)&Tb[(size_t)arow * K + ks * 32 + kgrp * 8];
#pragma unroll
      for (int nf = 0; nf < 16; ++nf) {
        bf16x8 bfg = *(const bf16x8*)&bl[((size_t)(ksl * 16 + nf) * 64 + lane) * 8];
        acc[nf] = __builtin_amdgcn_mfma_f32_16x16x32_bf16(af, bfg, acc[nf], 0, 0, 0);
      }
    }
  }
  const int ocol0 = lane & 15;
  const int orow0 = row0 + (lane >> 4) * 4;
#pragma unroll
  for (int nf = 0; nf < 16; ++nf) {
    int col = nf * 16 + ocol0;
    float bv = bias[col];
#pragma unroll
    for (int r = 0; r < 4; ++r) {
      int row = orow0 + r;
      if (row < nrows) outb[(size_t)row * HIDD + col] = f2b(fmaxf(acc[nf][r] + bv, 0.f));
    }
  }
}

// ---------------- Mean pool per graph (batch sorted, h in bf16) ---------------

__global__ void k_pool_partial(const ushort* __restrict__ hb, const int* __restrict__ batch,
                               float* __restrict__ fp) {  // fp[PCH][NGRAPH][HIDD]
  int b = blockIdx.x >> 3;
  int j = blockIdx.x & 7;
  __shared__ int srange[2];
  if (threadIdx.x < 2) {
    int target = b + threadIdx.x;
    int lo = 0, hi = NNODES;
    while (lo < hi) {
      int mid = (lo + hi) >> 1;
      if (batch[mid] < target) lo = mid + 1; else hi = mid;
    }
    srange[threadIdx.x] = lo;
  }
  __syncthreads();
  int s = srange[0], eend = srange[1];
  int len = eend - s;
  int cs = s + (int)((long long)len * j / PCH);
  int ce = s + (int)((long long)len * (j + 1) / PCH);
  int col = threadIdx.x;
  float acc = 0.f;
  for (int n = cs; n < ce; ++n) acc += bf1(hb[(size_t)n * HIDD + col]);
  fp[((size_t)j * NGRAPH + b) * HIDD + col] = acc;
}

// ---------------- pool-final + heads fused (block per graph) ------------------

__global__ void k_pool_heads(const float* __restrict__ fp, const int* __restrict__ batch,
                             const float* __restrict__ gf, const float* __restrict__ Wp,
                             const float* __restrict__ bp, const float* __restrict__ Wv,
                             const float* __restrict__ bv, float* __restrict__ out) {
  int b = blockIdx.x;
  __shared__ float f[FEATD];
  __shared__ int srange[2];
  if (threadIdx.x < 2) {
    int target = b + threadIdx.x;
    int lo = 0, hi = NNODES;
    while (lo < hi) {
      int mid = (lo + hi) >> 1;
      if (batch[mid] < target) lo = mid + 1; else hi = mid;
    }
    srange[threadIdx.x] = lo;
  }
  __syncthreads();
  int col = threadIdx.x;
  float acc = 0.f;
#pragma unroll
  for (int j = 0; j < PCH; ++j) acc += fp[((size_t)j * NGRAPH + b) * HIDD + col];
  float cnt = fmaxf((float)(srange[1] - srange[0]), 1.0f);
  f[col] = acc / cnt;
  if (col < GDIM) f[HIDD + col] = gf[b * GDIM + col];
  __syncthreads();
  if (col < NACT) {  // wave 0: logits
    float lg = bp[col];
    for (int k = 0; k < FEATD; ++k) lg = fmaf(f[k], Wp[k * NACT + col], lg);
    out[b * NACT + col] = lg;
  } else if (col < 128) {  // wave 1: value
    int t = col - 64;
    float pv = 0.f;
    for (int k = t; k < FEATD; k += 64) pv = fmaf(f[k], Wv[k], pv);
#pragma unroll
    for (int d = 32; d > 0; d >>= 1) pv += __shfl_down(pv, d);
    if (t == 0) out[NGRAPH * NACT + b] = pv + bv[0];
  }
}

// ---------------- launch ----------------

extern "C" void kernel_launch(void* const* d_in, const int* in_sizes, int n_in,
                              void* d_out, int out_size, void* d_ws, size_t ws_size,
                              hipStream_t stream) {
  const float* x   = (const float*)d_in[0];
  const float* ea  = (const float*)d_in[1];
  const float* gf  = (const float*)d_in[2];
  const float* We0 = (const float*)d_in[3];
  const float* W0  = (const float*)d_in[4];
  const float* b0  = (const float*)d_in[5];
  const float* We  = (const float*)d_in[6];
  const float* W   = (const float*)d_in[7];
  const float* bb  = (const float*)d_in[8];
  const float* Wp  = (const float*)d_in[9];
  const float* bp  = (const float*)d_in[10];
  const float* Wv  = (const float*)d_in[11];
  const float* bv  = (const float*)d_in[12];
  const int* eidx  = (const int*)d_in[13];
  const int* batch = (const int*)d_in[14];
  const int* esrc = eidx;
  const int* edst = eidx + NEDGES;

  char* w = (char*)d_ws;
  size_t p = 0;
  auto take = [&](size_t bytes) {
    size_t r = p;
    p += (bytes + 255) & ~(size_t)255;
    return r;
  };
  int* off      = (int*)(w + take((NNODES + 1) * 4));
  int* rank     = (int*)(w + take((size_t)NEDGES * 4));
  int* sums     = (int*)(w + take(1024));
  int* csr_src  = (int*)(w + take((size_t)NEDGES * 4));
  ushort* eab   = (ushort*)(w + take((size_t)NEDGES * FEDGE * 2));
  ushort* t0b   = (ushort*)(w + take((size_t)NNODES * FNODE * 2));
  ushort* xb    = (ushort*)(w + take((size_t)NNODES * FNODE * 2));
  ushort* tb    = (ushort*)(w + take((size_t)NNODES * HIDD * 2));
  ushort* hb    = (ushort*)(w + take((size_t)NNODES * HIDD * 2));
  uint* wep0    = (uint*)(w + take(128 * 4));
  uint* wepb    = (uint*)(w + take(3 * 1024 * 4));
  ushort* wp0   = (ushort*)(w + take((size_t)1024 * 8 * 2));
  ushort* wpb   = (ushort*)(w + take((size_t)3 * 8192 * 8 * 2));
  float* fp     = (float*)(w + take((size_t)PCH * NGRAPH * HIDD * 4));
  if (p > ws_size) return;  // workspace too small -> visible failure

  // CSR by dst: hist(+rank,+prep) -> scan -> atomic-free place
  k_zero_i32<<<(NNODES + 1 + 255) / 256, 256, 0, stream>>>(off, NNODES + 1);
  k_hist_prep<<<(NEDGES + 255) / 256, 256, 0, stream>>>(
      edst, off, rank, x, xb, We0, We, wep0, wepb, W0, W, wp0, wpb);
  int n_scan = NNODES + 1;
  int nb_scan = (n_scan + 1023) / 1024;
  k_scan1<<<nb_scan, 1024, 0, stream>>>(off, n_scan, sums);
  k_scan3<<<nb_scan, 1024, 0, stream>>>(off, n_scan, sums);
  k_place<<<(NEDGES + 255) / 256, 256, 0, stream>>>(esrc, edst, rank, off, ea,
                                                    csr_src, eab);

  const int gemm_grid = (NNODES + 63) / 64;  // 64 rows/block, 4 waves

  // layer 0
  k_edge32<<<NNODES / 4, 256, 0, stream>>>(x, xb, (const uint4*)eab, wep0, off,
                                           csr_src, t0b);
  k_gemm_mfma<FNODE><<<gemm_grid, 256, 0, stream>>>(t0b, wp0, b0, hb, NNODES);

  // layers 1..3: edge pull (bf16 gather, dot2) -> bf16 t -> MFMA GEMM -> bf16 h
  for (int l = 0; l < 3; ++l) {
    k_edge256<<<NNODES / 4, 256, 0, stream>>>(hb, (const uint4*)eab, wepb + l * 1024,
                                              off, csr_src, tb);
    k_gemm_mfma<HIDD><<<gemm_grid, 256, 0, stream>>>(
        tb, wpb + (size_t)l * 8192 * 8, bb + (size_t)l * HIDD, hb, NNODES);
  }

  // pool + heads
  k_pool_partial<<<NGRAPH * PCH, HIDD, 0, stream>>>(hb, batch, fp);
  k_pool_heads<<<NGRAPH, HIDD, 0, stream>>>(fp, batch, gf, Wp, bp, Wv, bv,
                                            (float*)d_out);
}